// Round 10
// baseline (2110.674 us; speedup 1.0000x reference)
//
#include <hip/hip_runtime.h>

#define SS 128
#define DD 768
#define HH 12
#define DHD 64
#define FF 3072
#define VV 50257
#define NCC 29
#define LL 12
#define SD (SS*DD)      // 98304
#define SF (SS*FF)      // 393216
#define TMAX (LL*NCC)   // 348

typedef unsigned short u16;
typedef __attribute__((ext_vector_type(8))) short short8;
typedef __attribute__((ext_vector_type(4))) float f32x4;

__device__ inline u16 f2bf(float f) {
    union { float f; unsigned u; } x; x.f = f;
    unsigned r = x.u + 0x7fffu + ((x.u >> 16) & 1u);
    return (u16)(r >> 16);
}

// ---------------- bitmask pack: lmu[i][t] bit j = rm[i*29+j][t]
__global__ void k_masku(const int* __restrict__ rm, unsigned* __restrict__ lmu) {
    int idx = blockIdx.x * 256 + threadIdx.x;
    if (idx >= LL * TMAX) return;
    int i = idx / TMAX, t = idx % TMAX;
    unsigned m = 0;
    for (int j = 0; j < 26; j++)
        m |= (unsigned)(rm[(size_t)(i * NCC + j) * TMAX + t] & 1) << j;
    lmu[idx] = m;
}

// ---------------- embedding
__global__ void k_embed(const int* __restrict__ ids, const float* __restrict__ wte,
                        const float* __restrict__ wpe, float* __restrict__ h) {
    int sd = blockIdx.x * 256 + threadIdx.x;
    if (sd >= SD) return;
    int s = sd / DD, d = sd % DD;
    h[sd] = wte[(size_t)ids[s] * DD + d] + wpe[sd];
}

// ---------------- f32 -> bf16 elementwise (wte)
__global__ void k_cvt(const float* __restrict__ in, u16* __restrict__ out, int n4) {
    int i = blockIdx.x * 256 + threadIdx.x;
    if (i >= n4) return;
    float4 v = *(const float4*)(in + (size_t)i * 4);
    u16* o = out + (size_t)i * 4;
    o[0] = f2bf(v.x); o[1] = f2bf(v.y); o[2] = f2bf(v.z); o[3] = f2bf(v.w);
}

// ---------------- qkv bias pack: [L][3*D] -> [L][12 heads][192]
__global__ void k_qkvb(const float* __restrict__ qkv_b, float* __restrict__ qkvbp) {
    int idx = blockIdx.x * 256 + threadIdx.x;
    if (idx >= LL * 3 * DD) return;
    int l = idx / (3 * DD), r = idx % (3 * DD);
    int p = r / DD, rem = r % DD, h = rem / DHD, j = rem % DHD;
    qkvbp[(size_t)l * 3 * DD + h * 192 + p * DHD + j] = qkv_b[idx];
}

// ---------------- weight transpose-convert (batched over layers via z)
__global__ __launch_bounds__(256) void k_wt(const float* __restrict__ W, u16* __restrict__ WT,
                                            int K, int N, int remap,
                                            long long sW, long long sWT) {
    __shared__ float T[64][65];
    const float* Wb = W + (size_t)blockIdx.z * sW;
    u16* WTb = WT + (size_t)blockIdx.z * sWT;
    int n0 = blockIdx.x * 64, k0 = blockIdx.y * 64;
    int c = threadIdx.x & 63, r0 = threadIdx.x >> 6;
#pragma unroll
    for (int i = 0; i < 16; i++) {
        int r = r0 + 4 * i;
        T[r][c] = Wb[(size_t)(k0 + r) * N + n0 + c];
    }
    __syncthreads();
    int ob = n0 >> 6;
    if (remap) { int p = ob / 12, h = ob % 12; ob = h * 3 + p; }
    size_t orow0 = (size_t)ob * 64;
#pragma unroll
    for (int i = 0; i < 16; i++) {
        int a = r0 + 4 * i;
        WTb[(orow0 + a) * K + k0 + c] = f2bf(T[c][a]);
    }
}

// ---------------- checks + fused prev-layer mproj reduce.
// Pre-phase (layer>0): reduce mpp partials for this 128-sd stripe -> LDS vred,
// write slots 13..28 of prev layer, compute h locally (no global h roundtrip).
// t-loop: 4 waves split t over Tm = T-16; wave 3 adds the 16 freshest rows from LDS.
__global__ __launch_bounds__(256) void k_check(
    const float* __restrict__ records, const unsigned* __restrict__ lmu,
    const float* __restrict__ h, float* __restrict__ rec0, float* __restrict__ x24,
    float* __restrict__ x3, int layer,
    const float* __restrict__ mpp, const float* __restrict__ resid,
    const float* __restrict__ proj_b_p, const float* __restrict__ mproj_b_p,
    float* __restrict__ recprev) {
    __shared__ float red[4][26][128];   // 53.2 KB
    __shared__ float vred[14][128];     // prev slots 13..26 values
    __shared__ float hloc[128];
    int lane = threadIdx.x & 63, w = threadIdx.x >> 6;
    int sd0 = blockIdx.x * 128;
    int d0 = sd0 % DD;
    int T = layer * NCC;
    if (layer > 0) {
        for (int idx = threadIdx.x; idx < 14 * 128; idx += 256) {
            int z = idx >> 7, sdl = idx & 127;
            const float* p = mpp + (size_t)z * 4 * SD + sd0 + sdl;
            vred[z][sdl] = p[0] + p[SD] + p[2 * SD] + p[3 * SD];
        }
        __syncthreads();
        if (threadIdx.x < 128) {
            int sdl = threadIdx.x;
            int sd = sd0 + sdl, d = d0 + sdl;
            float v0 = vred[0][sdl];
            float st = vred[13][sdl];
            float s4 = 0.f;
#pragma unroll
            for (int z = 1; z <= 12; z++) s4 += vred[z][sdl];
            float c5 = st - v0 - s4;
            float mb = mproj_b_p[d], pb = proj_b_p[d];
            float hn = resid[sd] + st + mb;
            hloc[sdl] = hn;
            recprev[(size_t)13 * SD + sd] = v0;
#pragma unroll
            for (int z = 1; z <= 12; z++) recprev[(size_t)(13 + z) * SD + sd] = vred[z][sdl];
            recprev[(size_t)26 * SD + sd] = c5;
            recprev[(size_t)27 * SD + sd] = mb;
            recprev[(size_t)28 * SD + sd] = pb;
            vred[13][sdl] = c5;   // t-loop reads slot26 = c5
        }
        __syncthreads();
    } else {
        if (threadIdx.x < 128) hloc[threadIdx.x] = h[sd0 + threadIdx.x];
        __syncthreads();
    }
    int sd = sd0 + lane * 2;
    int Tm = (layer > 0) ? T - 16 : 0;
    int Tq = (Tm + 3) >> 2;
    int tb = w * Tq, te = tb + Tq; if (te > Tm) te = Tm;
    float2 acc[26];
#pragma unroll
    for (int j = 0; j < 26; j++) { acc[j].x = 0.f; acc[j].y = 0.f; }
    const unsigned* lm = lmu + layer * TMAX;
    const float* rp = records + sd;
    int t = tb;
    for (; t + 8 <= te; t += 8) {
        float2 r[8];
        unsigned mv[8];
#pragma unroll
        for (int u = 0; u < 8; u++) r[u] = *(const float2*)(rp + (size_t)(t + u) * SD);
#pragma unroll
        for (int u = 0; u < 8; u++) mv[u] = lm[t + u];
#pragma unroll
        for (int u = 0; u < 8; u++) {
            unsigned m = __builtin_amdgcn_readfirstlane(mv[u]);
#pragma unroll
            for (int j = 0; j < 26; j++) {
                float mm = (m & (1u << j)) ? 1.0f : 0.0f;
                acc[j].x = fmaf(mm, r[u].x, acc[j].x);
                acc[j].y = fmaf(mm, r[u].y, acc[j].y);
            }
        }
    }
    for (; t < te; t++) {
        float2 r = *(const float2*)(rp + (size_t)t * SD);
        unsigned m = __builtin_amdgcn_readfirstlane(lm[t]);
#pragma unroll
        for (int j = 0; j < 26; j++) {
            float mm = (m & (1u << j)) ? 1.0f : 0.0f;
            acc[j].x = fmaf(mm, r.x, acc[j].x);
            acc[j].y = fmaf(mm, r.y, acc[j].y);
        }
    }
    if (layer > 0 && w == 3) {
        // freshest 16 rows (prev layer slots 13..28) from LDS / biases
#pragma unroll
        for (int c = 13; c <= 28; c++) {
            unsigned m = __builtin_amdgcn_readfirstlane(lm[Tm + c - 13]);
            float rx, ry;
            if (c <= 26) { rx = vred[c - 13][lane * 2]; ry = vred[c - 13][lane * 2 + 1]; }
            else if (c == 27) { rx = mproj_b_p[d0 + lane * 2]; ry = mproj_b_p[d0 + lane * 2 + 1]; }
            else { rx = proj_b_p[d0 + lane * 2]; ry = proj_b_p[d0 + lane * 2 + 1]; }
#pragma unroll
            for (int j = 0; j < 26; j++) {
                float mm = (m & (1u << j)) ? 1.0f : 0.0f;
                acc[j].x = fmaf(mm, rx, acc[j].x);
                acc[j].y = fmaf(mm, ry, acc[j].y);
            }
        }
    }
#pragma unroll
    for (int j = 0; j < 26; j++)
        *(float2*)&red[w][j][lane * 2] = acc[j];
    __syncthreads();
    for (int o = threadIdx.x; o < 26 * 128; o += 256) {
        int j = o >> 7, sdl = o & 127;
        float s = red[0][j][sdl] + red[1][j][sdl] + red[2][j][sdl] + red[3][j][sdl];
        float v = hloc[sdl] - s;
        float* dst;
        if (j == 0) dst = rec0;
        else if (j <= 12) dst = x24 + (size_t)(j - 1) * SD;
        else if (j == 13) dst = x3;
        else dst = x24 + (size_t)(12 + j - 14) * SD;
        dst[sd0 + sdl] = v;
    }
}

// ---------------- wave LayerNorm helper
__device__ inline void wave_ln(float (&vals)[12], int lane, const float* __restrict__ g,
                               const float* __restrict__ b) {
    float s = 0.f;
#pragma unroll
    for (int i = 0; i < 12; i++) s += vals[i];
#pragma unroll
    for (int m = 32; m >= 1; m >>= 1) s += __shfl_xor(s, m, 64);
    float mean = s * (1.f / DD);
    float vs = 0.f;
#pragma unroll
    for (int i = 0; i < 12; i++) { float d = vals[i] - mean; vs += d * d; }
#pragma unroll
    for (int m = 32; m >= 1; m >>= 1) vs += __shfl_xor(vs, m, 64);
    float rstd = rsqrtf(vs * (1.f / DD) + 1e-5f);
#pragma unroll
    for (int i = 0; i < 12; i++)
        vals[i] = (vals[i] - mean) * rstd * g[lane + 64 * i] + b[lane + 64 * i];
}

// ---------------- LayerNorm: 4 rows per 256-thread block
__global__ __launch_bounds__(256) void k_ln(const float* __restrict__ in, float* __restrict__ outf,
                                            u16* __restrict__ outb,
                                            const float* __restrict__ g, const float* __restrict__ b,
                                            int R) {
    int row = blockIdx.x * 4 + (threadIdx.x >> 6);
    if (row >= R) return;
    int lane = threadIdx.x & 63;
    const float* x = in + (size_t)row * DD;
    float vals[12];
#pragma unroll
    for (int i = 0; i < 12; i++) vals[i] = x[lane + 64 * i];
    wave_ln(vals, lane, g, b);
#pragma unroll
    for (int i = 0; i < 12; i++) {
        int d = lane + 64 * i;
        if (outf) outf[(size_t)row * DD + d] = vals[i];
        if (outb) outb[(size_t)row * DD + d] = f2bf(vals[i]);
    }
}

// ---------------- fused resid + MLP-A LN (4 rows/block over 14*SS rows)
__global__ __launch_bounds__(256) void k_rln(const float* __restrict__ reci,
                                             const float* __restrict__ x3,
                                             const float* __restrict__ tmp4,
                                             const float* __restrict__ proj_b_i,
                                             float* __restrict__ resid,
                                             u16* __restrict__ mlpAb,
                                             const float* __restrict__ l1g, const float* __restrict__ l1b,
                                             const float* __restrict__ l2g, const float* __restrict__ l2b) {
    int rowid = blockIdx.x * 4 + (threadIdx.x >> 6);
    int z = rowid >> 7, s = rowid & 127;
    int lane = threadIdx.x & 63;
    float vals[12];
    if (z == 0) {
        const float* src = x3 + (size_t)s * DD;
#pragma unroll
        for (int i = 0; i < 12; i++) vals[i] = src[lane + 64 * i];
        wave_ln(vals, lane, l1g, l1b);
    } else if (z <= 12) {
        const float* src = tmp4 + (size_t)(z - 1) * SD + (size_t)s * DD;
#pragma unroll
        for (int i = 0; i < 12; i++) vals[i] = src[lane + 64 * i];
    } else {
        const float* base = reci + (size_t)s * DD;
#pragma unroll
        for (int i = 0; i < 12; i++) {
            int d = lane + 64 * i;
            float a = base[d];
#pragma unroll
            for (int j = 1; j <= 12; j++) a += base[(size_t)j * SD + d];
            a += proj_b_i[d];
            vals[i] = a;
            resid[(size_t)s * DD + d] = a;
        }
    }
    wave_ln(vals, lane, l2g, l2b);
    u16* o = mlpAb + (size_t)z * SD + (size_t)s * DD;
#pragma unroll
    for (int i = 0; i < 12; i++) o[lane + 64 * i] = f2bf(vals[i]);
}

// ---------------- bf16 MFMA GEMM (M=128, N-tile=64) with register prefetch.
// Split-K via gridDim.y: partial kc writes Cv at (z*gridDim.y + kc).
__global__ __launch_bounds__(256) void k_mm(
    const u16* __restrict__ A, const u16* __restrict__ BT,
    const float* __restrict__ bias, void* __restrict__ Cv, void* __restrict__ Cv2,
    int N, int K, int lda, int ldbt, int ldc,
    long long sA, long long sBT, long long sC, long long sBias,
    int zMod, int zHi, int biasLo, int mode) {
    __shared__ u16 As[128][40];
    __shared__ u16 Bs[64][40];
    int z = blockIdx.z;
    int zb = z % zMod;
    const u16* Ab = A + (size_t)z * sA;
    const u16* Bb = BT + (size_t)zb * sBT;
    int n0 = blockIdx.x * 64;
    int nSplit = gridDim.y;
    int kLen = K / nSplit;
    int kOff = blockIdx.y * kLen;
    int kEnd = kOff + kLen;
    int tid = threadIdx.x;
    int lane = tid & 63, wid = tid >> 6;
    int wm = (wid >> 1) * 64, wn = (wid & 1) * 32;
    int l15 = lane & 15, l4 = lane >> 4;
    int sr = tid >> 2, sseg = tid & 3;
    int bn = n0 + sr;
    f32x4 acc[4][2];
#pragma unroll
    for (int i = 0; i < 4; i++) { acc[i][0] = (f32x4)0.f; acc[i][1] = (f32x4)0.f; }
    uint4 zero; zero.x = 0u; zero.y = 0u; zero.z = 0u; zero.w = 0u;
    uint4 a0 = *(const uint4*)(Ab + (size_t)sr * lda + kOff + sseg * 8);
    uint4 a1 = *(const uint4*)(Ab + (size_t)(sr + 64) * lda + kOff + sseg * 8);
    uint4 bv = (bn < N) ? *(const uint4*)(Bb + (size_t)bn * ldbt + kOff + sseg * 8) : zero;
    for (int k0 = kOff; k0 < kEnd; k0 += 32) {
        __syncthreads();
        *(uint4*)&As[sr][sseg * 8] = a0;
        *(uint4*)&As[sr + 64][sseg * 8] = a1;
        *(uint4*)&Bs[sr][sseg * 8] = bv;
        __syncthreads();
        if (k0 + 32 < kEnd) {
            a0 = *(const uint4*)(Ab + (size_t)sr * lda + k0 + 32 + sseg * 8);
            a1 = *(const uint4*)(Ab + (size_t)(sr + 64) * lda + k0 + 32 + sseg * 8);
            bv = (bn < N) ? *(const uint4*)(Bb + (size_t)bn * ldbt + k0 + 32 + sseg * 8) : zero;
        }
        short8 af[4], bfr[2];
#pragma unroll
        for (int i = 0; i < 4; i++) af[i] = *(const short8*)&As[wm + i * 16 + l15][l4 * 8];
#pragma unroll
        for (int j = 0; j < 2; j++) bfr[j] = *(const short8*)&Bs[wn + j * 16 + l15][l4 * 8];
#pragma unroll
        for (int i = 0; i < 4; i++)
#pragma unroll
            for (int j = 0; j < 2; j++)
                acc[i][j] = __builtin_amdgcn_mfma_f32_16x16x32_bf16(af[i], bfr[j], acc[i][j], 0, 0, 0);
    }
    const float* bp = (bias != nullptr && z >= biasLo) ? bias + (size_t)zb * sBias : nullptr;
    void* Cuse;
    int zc;
    if (nSplit > 1) { Cuse = Cv; zc = z * nSplit + blockIdx.y; }
    else { Cuse = (z >= zHi) ? Cv2 : Cv; zc = (z >= zHi) ? z - zHi : z; }
    if (mode == 0) {
        float* Cb = (float*)Cuse + (size_t)zc * sC;
#pragma unroll
        for (int i = 0; i < 4; i++) {
            int row = wm + i * 16 + l4 * 4;
#pragma unroll
            for (int j = 0; j < 2; j++) {
                int col = n0 + wn + j * 16 + l15;
                if (col >= N) continue;
                float bb = bp ? bp[col] : 0.f;
#pragma unroll
                for (int r = 0; r < 4; r++)
                    Cb[(size_t)(row + r) * ldc + col] = acc[i][j][r] + bb;
            }
        }
    } else {
        u16* Cb = (u16*)Cuse + (size_t)zc * sC;
#pragma unroll
        for (int i = 0; i < 4; i++) {
            int row = wm + i * 16 + l4 * 4;
#pragma unroll
            for (int j = 0; j < 2; j++) {
                int col = n0 + wn + j * 16 + l15;
                if (col >= N) continue;
                float bb = bp ? bp[col] : 0.f;
#pragma unroll
                for (int r = 0; r < 4; r++) {
                    float v = acc[i][j][r] + bb;
                    float c = v + 0.044715f * v * v * v;
                    float gv = 0.5f * v * (1.f + tanhf(0.7978845608028654f * c));
                    Cb[(size_t)(row + r) * ldc + col] = f2bf(gv);
                }
            }
        }
    }
}

// ---------------- fused attention + head projection.
// Reads 4-way split-K qkv partials; after PV converts ctx rows to bf16 in LDS
// and runs [16x64]x[64x768] MFMA mini-GEMM vs projT head-slice.
// z<12 -> outLo + z*SD (records slots 1..12); z>=12 -> outHi + (z-12)*SD (tmp4).
__global__ __launch_bounds__(256) void k_attnp(const float* __restrict__ qkvp,
                                               const float* __restrict__ qbias,
                                               const u16* __restrict__ projT,
                                               float* __restrict__ outLo,
                                               float* __restrict__ outHi) {
    __shared__ float kv[SS * DHD];
    __shared__ float qs[16][DHD];
    __shared__ float sc[16][130];
    __shared__ u16 cxs[16][72];
    int z = blockIdx.y, s0 = blockIdx.x * 16;
    int hb = z % 12;
    const float* p0 = qkvp + (size_t)z * 4 * (SS * 192);
    const float* p1 = p0 + SS * 192;
    const float* p2 = p1 + SS * 192;
    const float* p3 = p2 + SS * 192;
    const float* qb = qbias + (size_t)hb * 192;
    int tid = threadIdx.x;
    for (int idx = tid; idx < SS * DHD; idx += 256) {
        int t = idx >> 6, d = idx & 63;
        int o = t * 192 + 64 + d;
        kv[idx] = p0[o] + p1[o] + p2[o] + p3[o] + qb[64 + d];
    }
    for (int idx = tid; idx < 16 * DHD; idx += 256) {
        int r = idx >> 6, d = idx & 63;
        int o = (s0 + r) * 192 + d;
        qs[r][d] = p0[o] + p1[o] + p2[o] + p3[o] + qb[d];
    }
    __syncthreads();
    int r = tid >> 4, tt = tid & 15;
    int s = s0 + r;
    float pl[8];
#pragma unroll
    for (int u = 0; u < 8; u++) {
        int t = tt + 16 * u;
        float dot;
        if (t <= s) {
            dot = 0.f;
            for (int d = 0; d < DHD; d++) dot += qs[r][d] * kv[t * DHD + d];
            dot *= 0.125f;
        } else {
            dot = -1e30f;
        }
        pl[u] = dot;
    }
    float mx = pl[0];
#pragma unroll
    for (int u = 1; u < 8; u++) mx = fmaxf(mx, pl[u]);
#pragma unroll
    for (int m = 1; m < 16; m <<= 1) mx = fmaxf(mx, __shfl_xor(mx, m, 16));
    float sum = 0.f;
#pragma unroll
    for (int u = 0; u < 8; u++) { pl[u] = __expf(pl[u] - mx); sum += pl[u]; }
#pragma unroll
    for (int m = 1; m < 16; m <<= 1) sum += __shfl_xor(sum, m, 16);
    float inv = 1.f / sum;
#pragma unroll
    for (int u = 0; u < 8; u++) sc[r][tt + 16 * u] = pl[u] * inv;
    __syncthreads();
    for (int idx = tid; idx < SS * DHD; idx += 256) {
        int t = idx >> 6, d = idx & 63;
        int o = t * 192 + 128 + d;
        kv[idx] = p0[o] + p1[o] + p2[o] + p3[o] + qb[128 + d];
    }
    __syncthreads();
    int d = tid & 63, r0 = tid >> 6;
#pragma unroll
    for (int u = 0; u < 4; u++) {
        int rr = r0 + 4 * u;
        float a = 0.f;
        for (int t = 0; t < SS; t++) a += sc[rr][t] * kv[t * DHD + d];
        cxs[rr][d] = f2bf(a);
    }
    __syncthreads();
    // projection mini-GEMM: per wave 12 n-tiles of 16, K=64 (2 k-steps)
    int lane = tid & 63, w = tid >> 6;
    int l15 = lane & 15, l4 = lane >> 4;
    short8 af[2];
#pragma unroll
    for (int ks = 0; ks < 2; ks++) af[ks] = *(const short8*)&cxs[l15][ks * 32 + l4 * 8];
    float* ob = (z < 12) ? outLo + (size_t)z * SD : outHi + (size_t)(z - 12) * SD;
#pragma unroll
    for (int nt = 0; nt < 12; nt++) {
        int n0t = (w * 12 + nt) * 16;
        f32x4 acc = (f32x4)0.f;
#pragma unroll
        for (int ks = 0; ks < 2; ks++) {
            short8 bf = *(const short8*)(projT + (size_t)(n0t + l15) * DD + hb * DHD + ks * 32 + l4 * 8);
            acc = __builtin_amdgcn_mfma_f32_16x16x32_bf16(af[ks], bf, acc, 0, 0, 0);
        }
#pragma unroll
        for (int rr = 0; rr < 4; rr++)
            ob[(size_t)(s0 + l4 * 4 + rr) * DD + n0t + l15] = acc[rr];
    }
}

// ---------------- final h: h = resid + stream + mproj_b (layer 11)
__global__ void k_hfin(const float* __restrict__ mpp, const float* __restrict__ resid,
                       const float* __restrict__ mproj_b_i, float* __restrict__ h) {
    int sd = blockIdx.x * 256 + threadIdx.x;
    if (sd >= SD) return;
    int d = sd % DD;
    const float* p = mpp + (size_t)13 * 4 * SD + sd;
    float st = p[0] + p[SD] + p[2 * SD] + p[3 * SD];
    h[sd] = resid[sd] + st + mproj_b_i[d];
}

extern "C" void kernel_launch(void* const* d_in, const int* in_sizes, int n_in,
                              void* d_out, int out_size, void* d_ws, size_t ws_size,
                              hipStream_t stream) {
    const int* ids = (const int*)d_in[0];
    const int* rm = (const int*)d_in[2];
    const float* wte = (const float*)d_in[3];
    const float* wpe = (const float*)d_in[4];
    const float* qkv_w = (const float*)d_in[5];
    const float* qkv_b = (const float*)d_in[6];
    const float* proj_w = (const float*)d_in[7];
    const float* proj_b = (const float*)d_in[8];
    const float* ln1_g = (const float*)d_in[9];
    const float* ln1_b = (const float*)d_in[10];
    const float* ln2_g = (const float*)d_in[11];
    const float* ln2_b = (const float*)d_in[12];
    const float* fc_w = (const float*)d_in[13];
    const float* fc_b = (const float*)d_in[14];
    const float* mproj_w = (const float*)d_in[15];
    const float* mproj_b = (const float*)d_in[16];
    const float* lnf_g = (const float*)d_in[17];
    const float* lnf_b = (const float*)d_in[18];
    float* out = (float*)d_out;

    float* ws = (float*)d_ws;
    size_t off = 0;
    float* records = ws + off; off += (size_t)LL * NCC * SD;
    float* x24  = ws + off; off += (size_t)24 * SD;
    float* tmp4 = ws + off; off += (size_t)12 * SD;
    float* h    = ws + off; off += SD;
    float* x3   = ws + off; off += SD;
    float* resid= ws + off; off += SD;
    float* qkvp = ws + off; off += (size_t)24 * 4 * SS * 192;
    float* mpp  = ws + off; off += (size_t)14 * 4 * SD;
    float* qkvbp= ws + off; off += (size_t)LL * 3 * DD;
    u16* xlnb  = (u16*)(ws + off); off += (size_t)24 * SD / 2;
    u16* mlpAb = (u16*)(ws + off); off += (size_t)14 * SD / 2;
    u16* hfcb  = (u16*)(ws + off); off += (size_t)14 * SF / 2;
    u16* lnfb  = (u16*)(ws + off); off += SD / 2;
    u16* qkvhT = (u16*)(ws + off); off += (size_t)LL * 2304 * DD / 2;
    u16* fcT   = (u16*)(ws + off); off += (size_t)LL * FF * DD / 2;
    u16* mprojT= (u16*)(ws + off); off += (size_t)LL * DD * FF / 2;
    u16* projT = (u16*)(ws + off); off += (size_t)LL * DD * DD / 2;
    u16* wteb  = (u16*)(ws + off); off += (size_t)VV * DD / 2;
    unsigned* lmu = (unsigned*)(ws + off);

    k_masku<<<(LL * TMAX + 255) / 256, 256, 0, stream>>>(rm, lmu);
    k_embed<<<SD / 256, 256, 0, stream>>>(ids, wte, wpe, h);
    k_cvt<<<((VV * DD / 4) + 255) / 256, 256, 0, stream>>>(wte, wteb, VV * DD / 4);
    k_qkvb<<<(LL * 3 * DD + 255) / 256, 256, 0, stream>>>(qkv_b, qkvbp);
    k_wt<<<dim3(36, 12, 12), 256, 0, stream>>>(qkv_w, qkvhT, DD, 3 * DD, 1,
                                               (long long)DD * 3 * DD, (long long)2304 * DD);
    k_wt<<<dim3(48, 12, 12), 256, 0, stream>>>(fc_w, fcT, DD, FF, 0,
                                               (long long)DD * FF, (long long)FF * DD);
    k_wt<<<dim3(12, 48, 12), 256, 0, stream>>>(mproj_w, mprojT, FF, DD, 0,
                                               (long long)FF * DD, (long long)DD * FF);
    k_wt<<<dim3(12, 12, 12), 256, 0, stream>>>(proj_w, projT, DD, DD, 0,
                                               (long long)DD * DD, (long long)DD * DD);

    for (int i = 0; i < LL; i++) {
        float* reci = records + (size_t)i * NCC * SD;
        float* recprev = records + (size_t)(i > 0 ? i - 1 : 0) * NCC * SD;
        const float* pbp = proj_b + (size_t)(i > 0 ? i - 1 : 0) * DD;
        const float* mbp = mproj_b + (size_t)(i > 0 ? i - 1 : 0) * DD;
        const float* l1g = ln1_g + i * DD; const float* l1b = ln1_b + i * DD;
        const float* l2g = ln2_g + i * DD; const float* l2b = ln2_b + i * DD;
        const u16* qkvhTi = qkvhT + (size_t)i * 2304 * DD;
        const u16* fcTi = fcT + (size_t)i * FF * DD;
        const u16* mprojTi = mprojT + (size_t)i * DD * FF;
        const u16* projTi = projT + (size_t)i * DD * DD;

        // checks + fused prev-layer reduce
        k_check<<<SD / 128, 256, 0, stream>>>(records, lmu, h, reci, x24, x3, i,
                                              mpp, resid, pbp, mbp, recprev);

        k_ln<<<24 * SS / 4, 256, 0, stream>>>(x24, nullptr, xlnb, l1g, l1b, 24 * SS);
        // qkv split-K x4 -> qkvp partials (bias applied in attn staging)
        k_mm<<<dim3(3, 4, 24), 256, 0, stream>>>(
            xlnb, qkvhTi, nullptr, qkvp, nullptr,
            192, DD, DD, DD, 192, SD, (long long)192 * DD, (long long)SS * 192, 0, 12, 9999, 99, 0);
        // fused attention + head projection
        k_attnp<<<dim3(SS / 16, 24), 256, 0, stream>>>(qkvp, qkvbp + (size_t)i * 3 * DD,
                                                       projTi, reci + SD, tmp4);
        // fused resid + 14x LN -> mlpAb (z0=c3, z1..12=c4 heads, z13=stream)
        k_rln<<<14 * SS / 4, 256, 0, stream>>>(reci, x3, tmp4, proj_b + i * DD, resid, mlpAb,
                                               l1g, l1b, l2g, l2b);
        // fc batch 14 (672 blocks), fused gelu->bf16; bias only z=13 (stream)
        k_mm<<<dim3(48, 1, 14), 256, 0, stream>>>(
            mlpAb, fcTi, fc_b + (size_t)i * FF, hfcb, nullptr,
            FF, DD, DD, DD, FF, SD, 0, SF, 0, 1, 9999, 13, 1);
        // mproj split-K x4 (672 blocks) -> partials (reduced in next k_check / k_hfin)
        k_mm<<<dim3(12, 4, 14), 256, 0, stream>>>(
            hfcb, mprojTi, nullptr, mpp, nullptr,
            DD, FF, FF, FF, DD, SF, 0, SD, 0, 1, 9999, 99, 0);
    }

    k_hfin<<<SD / 256, 256, 0, stream>>>(mpp, resid, mproj_b + (size_t)11 * DD, h);
    k_ln<<<SS / 4, 256, 0, stream>>>(h, nullptr, lnfb, lnf_g, lnf_b, SS);
    k_mm<<<dim3((VV + 63) / 64, 1, 1), 256, 0, stream>>>(
        lnfb, wteb, nullptr, out, nullptr,
        VV, DD, DD, DD, VV, 0, 0, 0, 0, 1, 9999, 99, 0);
}

// Round 11
// 1802.098 us; speedup vs baseline: 1.1712x; 1.1712x over previous
//
#include <hip/hip_runtime.h>

#define SS 128
#define DD 768
#define HH 12
#define DHD 64
#define FF 3072
#define VV 50257
#define NCC 29
#define LL 12
#define SD (SS*DD)      // 98304
#define SF (SS*FF)      // 393216
#define TMAX (LL*NCC)   // 348

typedef unsigned short u16;
typedef __attribute__((ext_vector_type(8))) short short8;
typedef __attribute__((ext_vector_type(4))) float f32x4;

__device__ inline u16 f2bf(float f) {
    union { float f; unsigned u; } x; x.f = f;
    unsigned r = x.u + 0x7fffu + ((x.u >> 16) & 1u);
    return (u16)(r >> 16);
}

// ---------------- bitmask pack: lmu[i][t] bit j = rm[i*29+j][t]
__global__ void k_masku(const int* __restrict__ rm, unsigned* __restrict__ lmu) {
    int idx = blockIdx.x * 256 + threadIdx.x;
    if (idx >= LL * TMAX) return;
    int i = idx / TMAX, t = idx % TMAX;
    unsigned m = 0;
    for (int j = 0; j < 26; j++)
        m |= (unsigned)(rm[(size_t)(i * NCC + j) * TMAX + t] & 1) << j;
    lmu[idx] = m;
}

// ---------------- embedding
__global__ void k_embed(const int* __restrict__ ids, const float* __restrict__ wte,
                        const float* __restrict__ wpe, float* __restrict__ h) {
    int sd = blockIdx.x * 256 + threadIdx.x;
    if (sd >= SD) return;
    int s = sd / DD, d = sd % DD;
    h[sd] = wte[(size_t)ids[s] * DD + d] + wpe[sd];
}

// ---------------- f32 -> bf16 elementwise (wte)
__global__ void k_cvt(const float* __restrict__ in, u16* __restrict__ out, int n4) {
    int i = blockIdx.x * 256 + threadIdx.x;
    if (i >= n4) return;
    float4 v = *(const float4*)(in + (size_t)i * 4);
    u16* o = out + (size_t)i * 4;
    o[0] = f2bf(v.x); o[1] = f2bf(v.y); o[2] = f2bf(v.z); o[3] = f2bf(v.w);
}

// ---------------- qkv bias pack: [L][3*D] -> [L][12 heads][192]
__global__ void k_qkvb(const float* __restrict__ qkv_b, float* __restrict__ qkvbp) {
    int idx = blockIdx.x * 256 + threadIdx.x;
    if (idx >= LL * 3 * DD) return;
    int l = idx / (3 * DD), r = idx % (3 * DD);
    int p = r / DD, rem = r % DD, h = rem / DHD, j = rem % DHD;
    qkvbp[(size_t)l * 3 * DD + h * 192 + p * DHD + j] = qkv_b[idx];
}

// ---------------- weight transpose-convert (batched over layers via z)
__global__ __launch_bounds__(256) void k_wt(const float* __restrict__ W, u16* __restrict__ WT,
                                            int K, int N, int remap,
                                            long long sW, long long sWT) {
    __shared__ float T[64][65];
    const float* Wb = W + (size_t)blockIdx.z * sW;
    u16* WTb = WT + (size_t)blockIdx.z * sWT;
    int n0 = blockIdx.x * 64, k0 = blockIdx.y * 64;
    int c = threadIdx.x & 63, r0 = threadIdx.x >> 6;
#pragma unroll
    for (int i = 0; i < 16; i++) {
        int r = r0 + 4 * i;
        T[r][c] = Wb[(size_t)(k0 + r) * N + n0 + c];
    }
    __syncthreads();
    int ob = n0 >> 6;
    if (remap) { int p = ob / 12, h = ob % 12; ob = h * 3 + p; }
    size_t orow0 = (size_t)ob * 64;
#pragma unroll
    for (int i = 0; i < 16; i++) {
        int a = r0 + 4 * i;
        WTb[(orow0 + a) * K + k0 + c] = f2bf(T[c][a]);
    }
}

// ---------------- checks: 4 waves t-split over a 128-sd stripe, float2 loads,
// bitmask scalarized via readfirstlane, 8-deep prefetch, LDS cross-wave reduce
__global__ __launch_bounds__(256) void k_check(
    const float* __restrict__ records, const unsigned* __restrict__ lmu,
    const float* __restrict__ h, float* __restrict__ rec0, float* __restrict__ x24,
    float* __restrict__ x3, int layer) {
    __shared__ float red[4][26][128];   // 53.2 KB
    int lane = threadIdx.x & 63, w = threadIdx.x >> 6;
    int sd0 = blockIdx.x * 128;
    int sd = sd0 + lane * 2;
    int T = layer * NCC;
    int Tq = (T + 3) >> 2;
    int tb = w * Tq, te = tb + Tq; if (te > T) te = T;
    float2 acc[26];
#pragma unroll
    for (int j = 0; j < 26; j++) { acc[j].x = 0.f; acc[j].y = 0.f; }
    const unsigned* lm = lmu + layer * TMAX;
    const float* rp = records + sd;
    int t = tb;
    for (; t + 8 <= te; t += 8) {
        float2 r[8];
        unsigned mv[8];
#pragma unroll
        for (int u = 0; u < 8; u++) r[u] = *(const float2*)(rp + (size_t)(t + u) * SD);
#pragma unroll
        for (int u = 0; u < 8; u++) mv[u] = lm[t + u];
#pragma unroll
        for (int u = 0; u < 8; u++) {
            unsigned m = __builtin_amdgcn_readfirstlane(mv[u]);
#pragma unroll
            for (int j = 0; j < 26; j++) {
                float mm = (m & (1u << j)) ? 1.0f : 0.0f;
                acc[j].x = fmaf(mm, r[u].x, acc[j].x);
                acc[j].y = fmaf(mm, r[u].y, acc[j].y);
            }
        }
    }
    for (; t < te; t++) {
        float2 r = *(const float2*)(rp + (size_t)t * SD);
        unsigned m = __builtin_amdgcn_readfirstlane(lm[t]);
#pragma unroll
        for (int j = 0; j < 26; j++) {
            float mm = (m & (1u << j)) ? 1.0f : 0.0f;
            acc[j].x = fmaf(mm, r.x, acc[j].x);
            acc[j].y = fmaf(mm, r.y, acc[j].y);
        }
    }
#pragma unroll
    for (int j = 0; j < 26; j++)
        *(float2*)&red[w][j][lane * 2] = acc[j];
    __syncthreads();
    for (int o = threadIdx.x; o < 26 * 128; o += 256) {
        int j = o >> 7, sdl = o & 127;
        float s = red[0][j][sdl] + red[1][j][sdl] + red[2][j][sdl] + red[3][j][sdl];
        float v = h[sd0 + sdl] - s;
        float* dst;
        if (j == 0) dst = rec0;
        else if (j <= 12) dst = x24 + (size_t)(j - 1) * SD;
        else if (j == 13) dst = x3;
        else dst = x24 + (size_t)(12 + j - 14) * SD;
        dst[sd0 + sdl] = v;
    }
}

// ---------------- wave LayerNorm helper
__device__ inline void wave_ln(float (&vals)[12], int lane, const float* __restrict__ g,
                               const float* __restrict__ b) {
    float s = 0.f;
#pragma unroll
    for (int i = 0; i < 12; i++) s += vals[i];
#pragma unroll
    for (int m = 32; m >= 1; m >>= 1) s += __shfl_xor(s, m, 64);
    float mean = s * (1.f / DD);
    float vs = 0.f;
#pragma unroll
    for (int i = 0; i < 12; i++) { float d = vals[i] - mean; vs += d * d; }
#pragma unroll
    for (int m = 32; m >= 1; m >>= 1) vs += __shfl_xor(vs, m, 64);
    float rstd = rsqrtf(vs * (1.f / DD) + 1e-5f);
#pragma unroll
    for (int i = 0; i < 12; i++)
        vals[i] = (vals[i] - mean) * rstd * g[lane + 64 * i] + b[lane + 64 * i];
}

// ---------------- LayerNorm: 4 rows per 256-thread block
__global__ __launch_bounds__(256) void k_ln(const float* __restrict__ in, float* __restrict__ outf,
                                            u16* __restrict__ outb,
                                            const float* __restrict__ g, const float* __restrict__ b,
                                            int R) {
    int row = blockIdx.x * 4 + (threadIdx.x >> 6);
    if (row >= R) return;
    int lane = threadIdx.x & 63;
    const float* x = in + (size_t)row * DD;
    float vals[12];
#pragma unroll
    for (int i = 0; i < 12; i++) vals[i] = x[lane + 64 * i];
    wave_ln(vals, lane, g, b);
#pragma unroll
    for (int i = 0; i < 12; i++) {
        int d = lane + 64 * i;
        if (outf) outf[(size_t)row * DD + d] = vals[i];
        if (outb) outb[(size_t)row * DD + d] = f2bf(vals[i]);
    }
}

// ---------------- fused resid + MLP-A LN (4 rows/block over 14*SS rows)
__global__ __launch_bounds__(256) void k_rln(const float* __restrict__ reci,
                                             const float* __restrict__ x3,
                                             const float* __restrict__ tmp4,
                                             const float* __restrict__ proj_b_i,
                                             float* __restrict__ resid,
                                             u16* __restrict__ mlpAb,
                                             const float* __restrict__ l1g, const float* __restrict__ l1b,
                                             const float* __restrict__ l2g, const float* __restrict__ l2b) {
    int rowid = blockIdx.x * 4 + (threadIdx.x >> 6);
    int z = rowid >> 7, s = rowid & 127;
    int lane = threadIdx.x & 63;
    float vals[12];
    if (z == 0) {
        const float* src = x3 + (size_t)s * DD;
#pragma unroll
        for (int i = 0; i < 12; i++) vals[i] = src[lane + 64 * i];
        wave_ln(vals, lane, l1g, l1b);
    } else if (z <= 12) {
        const float* src = tmp4 + (size_t)(z - 1) * SD + (size_t)s * DD;
#pragma unroll
        for (int i = 0; i < 12; i++) vals[i] = src[lane + 64 * i];
    } else {
        const float* base = reci + (size_t)s * DD;
#pragma unroll
        for (int i = 0; i < 12; i++) {
            int d = lane + 64 * i;
            float a = base[d];
#pragma unroll
            for (int j = 1; j <= 12; j++) a += base[(size_t)j * SD + d];
            a += proj_b_i[d];
            vals[i] = a;
            resid[(size_t)s * DD + d] = a;
        }
    }
    wave_ln(vals, lane, l2g, l2b);
    u16* o = mlpAb + (size_t)z * SD + (size_t)s * DD;
#pragma unroll
    for (int i = 0; i < 12; i++) o[lane + 64 * i] = f2bf(vals[i]);
}

// ---------------- bf16 MFMA GEMM (M=128, N-tile=64) with register prefetch.
// Split-K via gridDim.y: partial kc writes Cv at (z*gridDim.y + kc).
__global__ __launch_bounds__(256) void k_mm(
    const u16* __restrict__ A, const u16* __restrict__ BT,
    const float* __restrict__ bias, void* __restrict__ Cv, void* __restrict__ Cv2,
    int N, int K, int lda, int ldbt, int ldc,
    long long sA, long long sBT, long long sC, long long sBias,
    int zMod, int zHi, int biasLo, int mode) {
    __shared__ u16 As[128][40];
    __shared__ u16 Bs[64][40];
    int z = blockIdx.z;
    int zb = z % zMod;
    const u16* Ab = A + (size_t)z * sA;
    const u16* Bb = BT + (size_t)zb * sBT;
    int n0 = blockIdx.x * 64;
    int nSplit = gridDim.y;
    int kLen = K / nSplit;
    int kOff = blockIdx.y * kLen;
    int kEnd = kOff + kLen;
    int tid = threadIdx.x;
    int lane = tid & 63, wid = tid >> 6;
    int wm = (wid >> 1) * 64, wn = (wid & 1) * 32;
    int l15 = lane & 15, l4 = lane >> 4;
    int sr = tid >> 2, sseg = tid & 3;
    int bn = n0 + sr;
    f32x4 acc[4][2];
#pragma unroll
    for (int i = 0; i < 4; i++) { acc[i][0] = (f32x4)0.f; acc[i][1] = (f32x4)0.f; }
    uint4 zero; zero.x = 0u; zero.y = 0u; zero.z = 0u; zero.w = 0u;
    uint4 a0 = *(const uint4*)(Ab + (size_t)sr * lda + kOff + sseg * 8);
    uint4 a1 = *(const uint4*)(Ab + (size_t)(sr + 64) * lda + kOff + sseg * 8);
    uint4 bv = (bn < N) ? *(const uint4*)(Bb + (size_t)bn * ldbt + kOff + sseg * 8) : zero;
    for (int k0 = kOff; k0 < kEnd; k0 += 32) {
        __syncthreads();
        *(uint4*)&As[sr][sseg * 8] = a0;
        *(uint4*)&As[sr + 64][sseg * 8] = a1;
        *(uint4*)&Bs[sr][sseg * 8] = bv;
        __syncthreads();
        if (k0 + 32 < kEnd) {
            a0 = *(const uint4*)(Ab + (size_t)sr * lda + k0 + 32 + sseg * 8);
            a1 = *(const uint4*)(Ab + (size_t)(sr + 64) * lda + k0 + 32 + sseg * 8);
            bv = (bn < N) ? *(const uint4*)(Bb + (size_t)bn * ldbt + k0 + 32 + sseg * 8) : zero;
        }
        short8 af[4], bfr[2];
#pragma unroll
        for (int i = 0; i < 4; i++) af[i] = *(const short8*)&As[wm + i * 16 + l15][l4 * 8];
#pragma unroll
        for (int j = 0; j < 2; j++) bfr[j] = *(const short8*)&Bs[wn + j * 16 + l15][l4 * 8];
#pragma unroll
        for (int i = 0; i < 4; i++)
#pragma unroll
            for (int j = 0; j < 2; j++)
                acc[i][j] = __builtin_amdgcn_mfma_f32_16x16x32_bf16(af[i], bfr[j], acc[i][j], 0, 0, 0);
    }
    const float* bp = (bias != nullptr && z >= biasLo) ? bias + (size_t)zb * sBias : nullptr;
    void* Cuse;
    int zc;
    if (nSplit > 1) { Cuse = Cv; zc = z * nSplit + blockIdx.y; }
    else { Cuse = (z >= zHi) ? Cv2 : Cv; zc = (z >= zHi) ? z - zHi : z; }
    if (mode == 0) {
        float* Cb = (float*)Cuse + (size_t)zc * sC;
#pragma unroll
        for (int i = 0; i < 4; i++) {
            int row = wm + i * 16 + l4 * 4;
#pragma unroll
            for (int j = 0; j < 2; j++) {
                int col = n0 + wn + j * 16 + l15;
                if (col >= N) continue;
                float bb = bp ? bp[col] : 0.f;
#pragma unroll
                for (int r = 0; r < 4; r++)
                    Cb[(size_t)(row + r) * ldc + col] = acc[i][j][r] + bb;
            }
        }
    } else {
        u16* Cb = (u16*)Cuse + (size_t)zc * sC;
#pragma unroll
        for (int i = 0; i < 4; i++) {
            int row = wm + i * 16 + l4 * 4;
#pragma unroll
            for (int j = 0; j < 2; j++) {
                int col = n0 + wn + j * 16 + l15;
                if (col >= N) continue;
                float bb = bp ? bp[col] : 0.f;
#pragma unroll
                for (int r = 0; r < 4; r++) {
                    float v = acc[i][j][r] + bb;
                    float c = v + 0.044715f * v * v * v;
                    float gv = 0.5f * v * (1.f + tanhf(0.7978845608028654f * c));
                    Cb[(size_t)(row + r) * ldc + col] = f2bf(gv);
                }
            }
        }
    }
}

// ---------------- fused attention + head projection.
// Reads 4-way split-K qkv partials; after PV converts ctx rows to bf16 in LDS
// and runs [16x64]x[64x768] MFMA mini-GEMM vs projT head-slice.
// z<12 -> outLo + z*SD (records slots 1..12); z>=12 -> outHi + (z-12)*SD (tmp4).
__global__ __launch_bounds__(256) void k_attnp(const float* __restrict__ qkvp,
                                               const float* __restrict__ qbias,
                                               const u16* __restrict__ projT,
                                               float* __restrict__ outLo,
                                               float* __restrict__ outHi) {
    __shared__ float kv[SS * DHD];
    __shared__ float qs[16][DHD];
    __shared__ float sc[16][130];
    __shared__ u16 cxs[16][72];
    int z = blockIdx.y, s0 = blockIdx.x * 16;
    int hb = z % 12;
    const float* p0 = qkvp + (size_t)z * 4 * (SS * 192);
    const float* p1 = p0 + SS * 192;
    const float* p2 = p1 + SS * 192;
    const float* p3 = p2 + SS * 192;
    const float* qb = qbias + (size_t)hb * 192;
    int tid = threadIdx.x;
    for (int idx = tid; idx < SS * DHD; idx += 256) {
        int t = idx >> 6, d = idx & 63;
        int o = t * 192 + 64 + d;
        kv[idx] = p0[o] + p1[o] + p2[o] + p3[o] + qb[64 + d];
    }
    for (int idx = tid; idx < 16 * DHD; idx += 256) {
        int r = idx >> 6, d = idx & 63;
        int o = (s0 + r) * 192 + d;
        qs[r][d] = p0[o] + p1[o] + p2[o] + p3[o] + qb[d];
    }
    __syncthreads();
    int r = tid >> 4, tt = tid & 15;
    int s = s0 + r;
    float pl[8];
#pragma unroll
    for (int u = 0; u < 8; u++) {
        int t = tt + 16 * u;
        float dot;
        if (t <= s) {
            dot = 0.f;
            for (int d = 0; d < DHD; d++) dot += qs[r][d] * kv[t * DHD + d];
            dot *= 0.125f;
        } else {
            dot = -1e30f;
        }
        pl[u] = dot;
    }
    float mx = pl[0];
#pragma unroll
    for (int u = 1; u < 8; u++) mx = fmaxf(mx, pl[u]);
#pragma unroll
    for (int m = 1; m < 16; m <<= 1) mx = fmaxf(mx, __shfl_xor(mx, m, 16));
    float sum = 0.f;
#pragma unroll
    for (int u = 0; u < 8; u++) { pl[u] = __expf(pl[u] - mx); sum += pl[u]; }
#pragma unroll
    for (int m = 1; m < 16; m <<= 1) sum += __shfl_xor(sum, m, 16);
    float inv = 1.f / sum;
#pragma unroll
    for (int u = 0; u < 8; u++) sc[r][tt + 16 * u] = pl[u] * inv;
    __syncthreads();
    for (int idx = tid; idx < SS * DHD; idx += 256) {
        int t = idx >> 6, d = idx & 63;
        int o = t * 192 + 128 + d;
        kv[idx] = p0[o] + p1[o] + p2[o] + p3[o] + qb[128 + d];
    }
    __syncthreads();
    int d = tid & 63, r0 = tid >> 6;
#pragma unroll
    for (int u = 0; u < 4; u++) {
        int rr = r0 + 4 * u;
        float a = 0.f;
        for (int t = 0; t < SS; t++) a += sc[rr][t] * kv[t * DHD + d];
        cxs[rr][d] = f2bf(a);
    }
    __syncthreads();
    // projection mini-GEMM: per wave 12 n-tiles of 16, K=64 (2 k-steps)
    int lane = tid & 63, w = tid >> 6;
    int l15 = lane & 15, l4 = lane >> 4;
    short8 af[2];
#pragma unroll
    for (int ks = 0; ks < 2; ks++) af[ks] = *(const short8*)&cxs[l15][ks * 32 + l4 * 8];
    float* ob = (z < 12) ? outLo + (size_t)z * SD : outHi + (size_t)(z - 12) * SD;
#pragma unroll
    for (int nt = 0; nt < 12; nt++) {
        int n0t = (w * 12 + nt) * 16;
        f32x4 acc = (f32x4)0.f;
#pragma unroll
        for (int ks = 0; ks < 2; ks++) {
            short8 bf = *(const short8*)(projT + (size_t)(n0t + l15) * DD + hb * DHD + ks * 32 + l4 * 8);
            acc = __builtin_amdgcn_mfma_f32_16x16x32_bf16(af[ks], bf, acc, 0, 0, 0);
        }
#pragma unroll
        for (int rr = 0; rr < 4; rr++)
            ob[(size_t)(s0 + l4 * 4 + rr) * DD + n0t + l15] = acc[rr];
    }
}

// ---------------- split-K reduce for mproj + c5 + slots 27/28 + h update
// part: [z*4+kc][SD] f32, z=0..13 (z0=c3, z1..12=c4 heads, z13=stream)
__global__ void k_red(const float* __restrict__ part, const float* __restrict__ resid,
                      const float* __restrict__ proj_b_i, const float* __restrict__ mproj_b_i,
                      float* __restrict__ reci, float* __restrict__ h) {
    int sd = blockIdx.x * 256 + threadIdx.x;
    if (sd >= SD) return;
    int d = sd % DD;
    float v0 = 0.f, s4 = 0.f, st = 0.f;
#pragma unroll
    for (int zz = 0; zz < 14; zz++) {
        const float* p = part + (size_t)zz * 4 * SD + sd;
        float v = p[0] + p[SD] + p[2 * SD] + p[3 * SD];
        if (zz == 0) { v0 = v; reci[(size_t)13 * SD + sd] = v; }
        else if (zz <= 12) { s4 += v; reci[(size_t)(13 + zz) * SD + sd] = v; }
        else st = v;
    }
    reci[(size_t)26 * SD + sd] = st - v0 - s4;
    reci[(size_t)27 * SD + sd] = mproj_b_i[d];
    reci[(size_t)28 * SD + sd] = proj_b_i[d];
    h[sd] = resid[sd] + st + mproj_b_i[d];
}

extern "C" void kernel_launch(void* const* d_in, const int* in_sizes, int n_in,
                              void* d_out, int out_size, void* d_ws, size_t ws_size,
                              hipStream_t stream) {
    const int* ids = (const int*)d_in[0];
    const int* rm = (const int*)d_in[2];
    const float* wte = (const float*)d_in[3];
    const float* wpe = (const float*)d_in[4];
    const float* qkv_w = (const float*)d_in[5];
    const float* qkv_b = (const float*)d_in[6];
    const float* proj_w = (const float*)d_in[7];
    const float* proj_b = (const float*)d_in[8];
    const float* ln1_g = (const float*)d_in[9];
    const float* ln1_b = (const float*)d_in[10];
    const float* ln2_g = (const float*)d_in[11];
    const float* ln2_b = (const float*)d_in[12];
    const float* fc_w = (const float*)d_in[13];
    const float* fc_b = (const float*)d_in[14];
    const float* mproj_w = (const float*)d_in[15];
    const float* mproj_b = (const float*)d_in[16];
    const float* lnf_g = (const float*)d_in[17];
    const float* lnf_b = (const float*)d_in[18];
    float* out = (float*)d_out;

    float* ws = (float*)d_ws;
    size_t off = 0;
    float* records = ws + off; off += (size_t)LL * NCC * SD;
    float* x24  = ws + off; off += (size_t)24 * SD;
    float* tmp4 = ws + off; off += (size_t)12 * SD;
    float* h    = ws + off; off += SD;
    float* x3   = ws + off; off += SD;
    float* resid= ws + off; off += SD;
    float* qkvp = ws + off; off += (size_t)24 * 4 * SS * 192;
    float* mpp  = ws + off; off += (size_t)14 * 4 * SD;
    float* qkvbp= ws + off; off += (size_t)LL * 3 * DD;
    u16* xlnb  = (u16*)(ws + off); off += (size_t)24 * SD / 2;
    u16* mlpAb = (u16*)(ws + off); off += (size_t)14 * SD / 2;
    u16* hfcb  = (u16*)(ws + off); off += (size_t)14 * SF / 2;
    u16* lnfb  = (u16*)(ws + off); off += SD / 2;
    u16* qkvhT = (u16*)(ws + off); off += (size_t)LL * 2304 * DD / 2;
    u16* fcT   = (u16*)(ws + off); off += (size_t)LL * FF * DD / 2;
    u16* mprojT= (u16*)(ws + off); off += (size_t)LL * DD * FF / 2;
    u16* projT = (u16*)(ws + off); off += (size_t)LL * DD * DD / 2;
    u16* wteb  = (u16*)(ws + off); off += (size_t)VV * DD / 2;
    unsigned* lmu = (unsigned*)(ws + off);

    k_masku<<<(LL * TMAX + 255) / 256, 256, 0, stream>>>(rm, lmu);
    k_embed<<<SD / 256, 256, 0, stream>>>(ids, wte, wpe, h);
    k_cvt<<<((VV * DD / 4) + 255) / 256, 256, 0, stream>>>(wte, wteb, VV * DD / 4);
    k_qkvb<<<(LL * 3 * DD + 255) / 256, 256, 0, stream>>>(qkv_b, qkvbp);
    k_wt<<<dim3(36, 12, 12), 256, 0, stream>>>(qkv_w, qkvhT, DD, 3 * DD, 1,
                                               (long long)DD * 3 * DD, (long long)2304 * DD);
    k_wt<<<dim3(48, 12, 12), 256, 0, stream>>>(fc_w, fcT, DD, FF, 0,
                                               (long long)DD * FF, (long long)FF * DD);
    k_wt<<<dim3(12, 48, 12), 256, 0, stream>>>(mproj_w, mprojT, FF, DD, 0,
                                               (long long)FF * DD, (long long)DD * FF);
    k_wt<<<dim3(12, 12, 12), 256, 0, stream>>>(proj_w, projT, DD, DD, 0,
                                               (long long)DD * DD, (long long)DD * DD);

    for (int i = 0; i < LL; i++) {
        float* reci = records + (size_t)i * NCC * SD;
        const float* l1g = ln1_g + i * DD; const float* l1b = ln1_b + i * DD;
        const float* l2g = ln2_g + i * DD; const float* l2b = ln2_b + i * DD;
        const u16* qkvhTi = qkvhT + (size_t)i * 2304 * DD;
        const u16* fcTi = fcT + (size_t)i * FF * DD;
        const u16* mprojTi = mprojT + (size_t)i * DD * FF;
        const u16* projTi = projT + (size_t)i * DD * DD;

        k_check<<<SD / 128, 256, 0, stream>>>(records, lmu, h, reci, x24, x3, i);

        k_ln<<<24 * SS / 4, 256, 0, stream>>>(x24, nullptr, xlnb, l1g, l1b, 24 * SS);
        // qkv split-K x4 -> qkvp partials (bias applied in attn staging)
        k_mm<<<dim3(3, 4, 24), 256, 0, stream>>>(
            xlnb, qkvhTi, nullptr, qkvp, nullptr,
            192, DD, DD, DD, 192, SD, (long long)192 * DD, (long long)SS * 192, 0, 12, 9999, 99, 0);
        // fused attention + head projection: head2 -> records slots 1..12, head4 -> tmp4
        k_attnp<<<dim3(SS / 16, 24), 256, 0, stream>>>(qkvp, qkvbp + (size_t)i * 3 * DD,
                                                       projTi, reci + SD, tmp4);
        // fused resid + 14x LN -> mlpAb (z0=c3, z1..12=c4 heads, z13=stream)
        k_rln<<<14 * SS / 4, 256, 0, stream>>>(reci, x3, tmp4, proj_b + i * DD, resid, mlpAb,
                                               l1g, l1b, l2g, l2b);
        // fc batch 14 (672 blocks), fused gelu->bf16; bias only z=13 (stream)
        k_mm<<<dim3(48, 1, 14), 256, 0, stream>>>(
            mlpAb, fcTi, fc_b + (size_t)i * FF, hfcb, nullptr,
            FF, DD, DD, DD, FF, SD, 0, SF, 0, 1, 9999, 13, 1);
        // mproj split-K x4 (672 blocks) -> partials
        k_mm<<<dim3(12, 4, 14), 256, 0, stream>>>(
            hfcb, mprojTi, nullptr, mpp, nullptr,
            DD, FF, FF, FF, DD, SF, 0, SD, 0, 1, 9999, 99, 0);
        // reduce partials -> slots 13..26 + c5 + slots 27/28 + h
        k_red<<<SD / 256, 256, 0, stream>>>(mpp, resid, proj_b + i * DD, mproj_b + i * DD,
                                            reci, h);
    }

    k_ln<<<SS / 4, 256, 0, stream>>>(h, nullptr, lnfb, lnf_g, lnf_b, SS);
    k_mm<<<dim3((VV + 63) / 64, 1, 1), 256, 0, stream>>>(
        lnfb, wteb, nullptr, out, nullptr,
        VV, DD, DD, DD, VV, 0, 0, 0, 0, 1, 9999, 99, 0);
}